// Round 2
// baseline (4447.282 us; speedup 1.0000x reference)
//
#include <hip/hip_runtime.h>
#include <hip/hip_bf16.h>

// WMSA fused kernel, round 2: dtype-sniffing correctness build.
// One block (256 threads) per window. B=16, C=96, H=W=224, M=7, NH=3, Hd=32.
// Detects f32-vs-bf16 device buffers at runtime (uniform per-block branch).

#define CH     96
#define NHEAD  3
#define HD     32
#define MM     49
#define MW     7
#define HWDIM  224
#define WPITCH 100   // win/wbuf pitch (float), %4==0 for float4 reads
#define QPITCH 292   // qkv pitch
#define SPITCH 52    // score pitch

__device__ __forceinline__ float bf2f(__hip_bfloat16 v) { return __bfloat162float(v); }

extern "C" __global__ void __launch_bounds__(256)
wmsa_fused(const void* __restrict__ xv,
           const void* __restrict__ qkvw_v,
           const void* __restrict__ qkvb_v,
           const void* __restrict__ bias_v,
           const void* __restrict__ outw_v,
           const void* __restrict__ outb_v,
           void* __restrict__ out_v)
{
    __shared__ float win[MM][WPITCH];    // window input, later reused as PV output (stack)
    __shared__ float qkv[MM][QPITCH];    // qkv[t][o], o = h*96 + {0:q,32:k,64:v} + d
    __shared__ float wbuf[CH][WPITCH];   // staged weight chunk (96 x 96)
    __shared__ float sbuf[MM][SPITCH];   // attention scores / exp values
    __shared__ float lrow[MM];           // softmax denominators
    __shared__ float bias_lds[169 * 3];  // relative-position bias (f32)
    __shared__ int   s_hits;

    const int tid = threadIdx.x;
    const int wid = blockIdx.x;
    const int b   = wid >> 10;           // batch
    const int w   = wid & 1023;          // window index (wr*32+wc)
    const int h0  = (w >> 5) * MW;
    const int w0  = (w & 31) * MW;

    // ---- dtype sniff: bf16-interpret first 2048 halfwords of x; count |v|>=128 ----
    if (tid == 0) s_hits = 0;
    __syncthreads();
    {
        const unsigned short* u16 = (const unsigned short*)xv;
        int local = 0;
        for (int i = tid; i < 2048; i += 256) {
            unsigned e = (u16[i] >> 7) & 0xFFu;
            local += (e >= 0x86u) ? 1 : 0;   // |bf16| >= 128: impossible for N(0,1) bf16 data
        }
        atomicAdd(&s_hits, local);
    }
    __syncthreads();
    const bool F32 = (s_hits > 32);      // f32 bits misread as bf16 -> ~480 hits

    const float* xf = (const float*)xv;
    const __hip_bfloat16* xh = (const __hip_bfloat16*)xv;

    // ---- stage bias table ----
    for (int i = tid; i < 169 * 3; i += 256)
        bias_lds[i] = F32 ? ((const float*)bias_v)[i] : bf2f(((const __hip_bfloat16*)bias_v)[i]);

    // ---- load window: win[t][c] = x[b, c, h0+i, w0+j] ----
    for (int idx = tid; idx < MM * CH; idx += 256) {
        int c = idx / MM;
        int t = idx - c * MM;
        int i = t / MW, j = t - i * MW;
        int gi = (((b * CH + c) * HWDIM) + h0 + i) * HWDIM + w0 + j;
        win[t][c] = F32 ? xf[gi] : bf2f(xh[gi]);
    }
    __syncthreads();

    const int tx = tid & 15;   // output-channel group
    const int ty = tid >> 4;   // row group

    // ==== QKV projection: qkv[t][o] = sum_c win[t][c]*qkv_w[o][c] + qkv_b[o] ====
    for (int ob = 0; ob < 3; ++ob) {
        if (F32) {
            const float* qw = (const float*)qkvw_v;
            for (int idx = tid; idx < CH * 24; idx += 256) {      // 24 chunks of 4
                int r  = idx / 24;
                int c4 = (idx - r * 24) * 4;
                float4 v = *(const float4*)&qw[(ob * CH + r) * CH + c4];
                *(float4*)&wbuf[r][c4] = v;
            }
        } else {
            const __hip_bfloat16* qw = (const __hip_bfloat16*)qkvw_v;
            for (int idx = tid; idx < CH * 12; idx += 256) {      // 12 chunks of 8
                int r  = idx / 12;
                int c8 = (idx - r * 12) * 8;
                union { uint4 u; __hip_bfloat16 h[8]; } blk;
                blk.u = *(const uint4*)&qw[(ob * CH + r) * CH + c8];
                #pragma unroll
                for (int e = 0; e < 8; ++e) wbuf[r][c8 + e] = bf2f(blk.h[e]);
            }
        }
        __syncthreads();

        float acc[4][6];
        #pragma unroll
        for (int r = 0; r < 4; ++r)
            #pragma unroll
            for (int j = 0; j < 6; ++j) acc[r][j] = 0.f;

        for (int c = 0; c < CH; c += 4) {
            float4 av[4];
            #pragma unroll
            for (int r = 0; r < 4; ++r) {
                int t = ty + 16 * r; if (t > MM - 1) t = MM - 1;
                av[r] = *(const float4*)&win[t][c];
            }
            #pragma unroll
            for (int j = 0; j < 6; ++j) {
                float4 wv = *(const float4*)&wbuf[tx + 16 * j][c];
                #pragma unroll
                for (int r = 0; r < 4; ++r) {
                    acc[r][j] = fmaf(av[r].x, wv.x, acc[r][j]);
                    acc[r][j] = fmaf(av[r].y, wv.y, acc[r][j]);
                    acc[r][j] = fmaf(av[r].z, wv.z, acc[r][j]);
                    acc[r][j] = fmaf(av[r].w, wv.w, acc[r][j]);
                }
            }
        }
        #pragma unroll
        for (int r = 0; r < 4; ++r) {
            int t = ty + 16 * r;
            if (t < MM) {
                #pragma unroll
                for (int j = 0; j < 6; ++j) {
                    int o = ob * CH + tx + 16 * j;
                    float bb = F32 ? ((const float*)qkvb_v)[o] : bf2f(((const __hip_bfloat16*)qkvb_v)[o]);
                    qkv[t][o] = acc[r][j] + bb;
                }
            }
        }
        __syncthreads();
    }

    // ==== attention, per head ====
    const float inv_scale = 0.018042196f;  // sqrt(3)/96
    for (int h = 0; h < NHEAD; ++h) {
        // -- scores S[p][q] = (q_p . k_q)/scale + bias --
        for (int idx = tid; idx < MM * MM; idx += 256) {
            int p = idx / MM;
            int q = idx - p * MM;
            const float* qp = &qkv[p][h * CH];
            const float* kp = &qkv[q][h * CH + HD];
            float4 a4 = {0.f, 0.f, 0.f, 0.f};
            #pragma unroll
            for (int d = 0; d < HD; d += 4) {
                float4 qa = *(const float4*)&qp[d];
                float4 kb = *(const float4*)&kp[d];
                a4.x = fmaf(qa.x, kb.x, a4.x);
                a4.y = fmaf(qa.y, kb.y, a4.y);
                a4.z = fmaf(qa.z, kb.z, a4.z);
                a4.w = fmaf(qa.w, kb.w, a4.w);
            }
            float sv = (a4.x + a4.y + a4.z + a4.w) * inv_scale;
            int i1 = p / MW, j1 = p - i1 * MW;
            int i2 = q / MW, j2 = q - i2 * MW;
            int bidx = (i1 - i2 + 6) * 13 + (j1 - j2 + 6);
            sv += bias_lds[bidx * 3 + h];
            sbuf[p][q] = sv;
        }
        __syncthreads();

        // -- serial per-row softmax (49 threads), normalize deferred to PV --
        if (tid < MM) {
            int p = tid;
            float m = -1e30f;
            for (int q = 0; q < MM; ++q) m = fmaxf(m, sbuf[p][q]);
            float l = 0.f;
            for (int q = 0; q < MM; ++q) {
                float e = __expf(sbuf[p][q] - m);
                sbuf[p][q] = e;
                l += e;
            }
            lrow[p] = l;
        }
        __syncthreads();

        // -- PV: stack[p][h*32+d] = (sum_q e[p][q] * v[q][d]) / lrow[p] --
        for (int idx = tid; idx < MM * 8; idx += 256) {
            int p  = idx >> 3;
            int d4 = (idx & 7) * 4;
            float4 acc = {0.f, 0.f, 0.f, 0.f};
            for (int q = 0; q < MM; ++q) {
                float e = sbuf[p][q];
                float4 v4 = *(const float4*)&qkv[q][h * CH + 2 * HD + d4];
                acc.x = fmaf(e, v4.x, acc.x);
                acc.y = fmaf(e, v4.y, acc.y);
                acc.z = fmaf(e, v4.z, acc.z);
                acc.w = fmaf(e, v4.w, acc.w);
            }
            float invl = 1.0f / lrow[p];
            float4 res = {acc.x * invl, acc.y * invl, acc.z * invl, acc.w * invl};
            *(float4*)&win[p][h * HD + d4] = res;  // win reused as 'stack'
        }
        __syncthreads();
    }

    // ==== output projection ====
    if (F32) {
        const float* ow = (const float*)outw_v;
        for (int idx = tid; idx < CH * 24; idx += 256) {
            int r  = idx / 24;
            int c4 = (idx - r * 24) * 4;
            float4 v = *(const float4*)&ow[r * CH + c4];
            *(float4*)&wbuf[r][c4] = v;
        }
    } else {
        const __hip_bfloat16* ow = (const __hip_bfloat16*)outw_v;
        for (int idx = tid; idx < CH * 12; idx += 256) {
            int r  = idx / 12;
            int c8 = (idx - r * 12) * 8;
            union { uint4 u; __hip_bfloat16 h[8]; } blk;
            blk.u = *(const uint4*)&ow[r * CH + c8];
            #pragma unroll
            for (int e = 0; e < 8; ++e) wbuf[r][c8 + e] = bf2f(blk.h[e]);
        }
    }
    __syncthreads();

    {
        float acc[4][6];
        #pragma unroll
        for (int r = 0; r < 4; ++r)
            #pragma unroll
            for (int j = 0; j < 6; ++j) acc[r][j] = 0.f;

        for (int c = 0; c < CH; c += 4) {
            float4 av[4];
            #pragma unroll
            for (int r = 0; r < 4; ++r) {
                int t = ty + 16 * r; if (t > MM - 1) t = MM - 1;
                av[r] = *(const float4*)&win[t][c];
            }
            #pragma unroll
            for (int j = 0; j < 6; ++j) {
                float4 wv = *(const float4*)&wbuf[tx + 16 * j][c];
                #pragma unroll
                for (int r = 0; r < 4; ++r) {
                    acc[r][j] = fmaf(av[r].x, wv.x, acc[r][j]);
                    acc[r][j] = fmaf(av[r].y, wv.y, acc[r][j]);
                    acc[r][j] = fmaf(av[r].z, wv.z, acc[r][j]);
                    acc[r][j] = fmaf(av[r].w, wv.w, acc[r][j]);
                }
            }
        }

        // epilogue: source reshapes (nW*MM) directly to (H,W): flat = w*49 + t
        #pragma unroll
        for (int r = 0; r < 4; ++r) {
            int t = ty + 16 * r;
            if (t < MM) {
                int flat = w * MM + t;
                int ho = flat / HWDIM;
                int wo = flat - ho * HWDIM;
                #pragma unroll
                for (int j = 0; j < 6; ++j) {
                    int o = tx + 16 * j;
                    float bb = F32 ? ((const float*)outb_v)[o] : bf2f(((const __hip_bfloat16*)outb_v)[o]);
                    float val = acc[r][j] + bb;
                    int gi = ((b * CH + o) * HWDIM + ho) * HWDIM + wo;
                    if (F32) ((float*)out_v)[gi] = val;
                    else     ((__hip_bfloat16*)out_v)[gi] = __float2bfloat16(val);
                }
            }
        }
    }
}

extern "C" void kernel_launch(void* const* d_in, const int* in_sizes, int n_in,
                              void* d_out, int out_size, void* d_ws, size_t ws_size,
                              hipStream_t stream) {
    int B = in_sizes[0] / (CH * HWDIM * HWDIM);   // 16 (element count is dtype-agnostic)
    int nblocks = B * 1024;                        // one block per window
    wmsa_fused<<<nblocks, 256, 0, stream>>>(d_in[0], d_in[1], d_in[2], d_in[3],
                                            d_in[4], d_in[5], d_out);
}

// Round 3
// 942.018 us; speedup vs baseline: 4.7210x; 4.7210x over previous
//
#include <hip/hip_runtime.h>
#include <hip/hip_bf16.h>

// WMSA round 3: MFMA (bf16) fused kernel. Buffers confirmed f32 (WRITE_SIZE evidence).
// One block (256 thr = 4 waves) per window; wave wv owns output rows [16wv, 16wv+16).
// Pre-kernel converts weights to bf16 into d_ws.

#define CH    96
#define MMTOK 49
#define HWD   224

typedef __attribute__((ext_vector_type(8))) __bf16 bfrag;
typedef __attribute__((ext_vector_type(4))) float  f4;
#define MFMA(a,b,c) __builtin_amdgcn_mfma_f32_16x16x32_bf16(a,b,c,0,0,0)

// ws layout (bf16 element offsets)
#define WS_QW  0        // qkv_w [288][96]
#define WS_QB  27648    // qkv_b [288]
#define WS_OW  27936    // out_w [96][96]
#define WS_OB  37152    // out_b [96]
#define WS_BT  37248    // bias_table [507]
#define WS_TOT 37755

// LDS pitches (bf16 elems). Chosen so pitch-in-dwords mod 32 avoids heavy
// bank conflicts on ds_read_b128 (pitch/2 mod 32: 104->20, 216->12, 88->12).
#define PW_WIN 104
#define PW_W   104
#define PW_QK  216
#define PW_VT  88
#define PW_P   88

extern "C" __global__ void __launch_bounds__(256)
cvt_weights(const float* __restrict__ qw, const float* __restrict__ qb,
            const float* __restrict__ ow, const float* __restrict__ ob,
            const float* __restrict__ bt, __hip_bfloat16* __restrict__ ws)
{
    int i = blockIdx.x * 256 + threadIdx.x;
    if (i >= WS_TOT) return;
    float v;
    if      (i < WS_QB) v = qw[i];
    else if (i < WS_OW) v = qb[i - WS_QB];
    else if (i < WS_OB) v = ow[i - WS_OW];
    else if (i < WS_BT) v = ob[i - WS_OB];
    else                v = bt[i - WS_BT];
    ws[i] = __float2bfloat16(v);
}

extern "C" __global__ void __launch_bounds__(256)
wmsa_mfma(const float* __restrict__ x,
          const __hip_bfloat16* __restrict__ ws,
          float* __restrict__ out)
{
    __shared__ __align__(16) __hip_bfloat16 s_win[64 * PW_WIN];  // window in, later 'stack'
    __shared__ __align__(16) __hip_bfloat16 s_w  [96 * PW_W];    // weight chunk; P overlays
    __shared__ __align__(16) __hip_bfloat16 s_qk [64 * PW_QK];   // [t][h*64 + (K?32:0) + d]
    __shared__ __align__(16) __hip_bfloat16 s_vT [96 * PW_VT];   // [(h*32+d)][t]
    __shared__ float s_bias[507];

    const int tid  = threadIdx.x;
    // XCD-bijective swizzle: gridDim.x % 8 == 0 (16384)
    const int cpx  = gridDim.x >> 3;
    const int wid  = (blockIdx.x & 7) * cpx + (blockIdx.x >> 3);
    const int b    = wid >> 10;
    const int w    = wid & 1023;
    const int h0   = (w >> 5) * 7;
    const int w0   = (w & 31) * 7;
    const int lane = tid & 63;
    const int wv   = tid >> 6;
    const int lr   = lane & 15;
    const int lg   = lane >> 4;
    const int trow = wv * 16 + lg * 4;   // C-tile row base for this lane

    const __hip_bfloat16* QW = ws + WS_QW;
    const __hip_bfloat16* QB = ws + WS_QB;
    const __hip_bfloat16* OW = ws + WS_OW;
    const __hip_bfloat16* OB = ws + WS_OB;
    const __hip_bfloat16* BT = ws + WS_BT;

    // ---- stage bias table (f32 in LDS) ----
    for (int i = tid; i < 507; i += 256) s_bias[i] = __bfloat162float(BT[i]);

    // ---- load window -> s_win bf16, rows 49..63 zeroed ----
    for (int idx = tid; idx < 64 * CH; idx += 256) {
        int t = idx & 63, c = idx >> 6;
        float v = 0.f;
        if (t < MMTOK) {
            int i = t / 7, j = t - i * 7;
            v = x[((b * CH + c) * HWD + h0 + i) * HWD + w0 + j];
        }
        s_win[t * PW_WIN + c] = __float2bfloat16(v);
    }
    __syncthreads();

    // A-fragments for QKV GEMM (rows wv*16+lr, K=96 = 3 kblocks)
    bfrag aq[3];
    #pragma unroll
    for (int k = 0; k < 3; ++k)
        aq[k] = *(const bfrag*)&s_win[(wv * 16 + lr) * PW_WIN + k * 32 + lg * 8];

    // ==== QKV GEMM, 3 chunks of 96 output cols (chunk ob == head ob) ====
    for (int ob = 0; ob < 3; ++ob) {
        if (ob) __syncthreads();                 // prev chunk GEMM done before restage
        for (int idx = tid; idx < 96 * 12; idx += 256) {
            int r = idx / 12, c8 = (idx - r * 12) * 8;
            *(uint4*)&s_w[r * PW_W + c8] = *(const uint4*)&QW[(ob * 96 + r) * 96 + c8];
        }
        __syncthreads();

        f4 acc[6];
        #pragma unroll
        for (int n = 0; n < 6; ++n) {
            float bb = __bfloat162float(QB[ob * 96 + n * 16 + lr]);
            acc[n] = f4{bb, bb, bb, bb};
        }
        #pragma unroll
        for (int k = 0; k < 3; ++k)
            #pragma unroll
            for (int n = 0; n < 6; ++n) {
                bfrag bf = *(const bfrag*)&s_w[(n * 16 + lr) * PW_W + k * 32 + lg * 8];
                acc[n] = MFMA(aq[k], bf, acc[n]);
            }

        // C-store: n=0,1 -> Q ; n=2,3 -> K ; n=4,5 -> V(transposed)
        #pragma unroll
        for (int n = 0; n < 6; ++n) {
            int part = n >> 1;
            int d = ((n & 1) << 4) + lr;
            #pragma unroll
            for (int r = 0; r < 4; ++r) {
                __hip_bfloat16 hv = __float2bfloat16(acc[n][r]);
                int t = trow + r;
                if (part < 2) s_qk[t * PW_QK + ob * 64 + part * 32 + d] = hv;
                else          s_vT[(ob * 32 + d) * PW_VT + t] = hv;
            }
        }
    }
    __syncthreads();

    // ==== attention ====
    __hip_bfloat16* s_P = s_w;                  // overlay: [64][PW_P]
    const float inv_scale = 0.0180421959f;      // sqrt(3)/96

    int a1[4];
    #pragma unroll
    for (int r = 0; r < 4; ++r) {
        int p = trow + r, i1 = p / 7, j1 = p - 7 * i1;
        a1[r] = (i1 * 13 + j1) * 3;
    }
    int a2[4]; bool qok[4];
    #pragma unroll
    for (int n = 0; n < 4; ++n) {
        int q = n * 16 + lr, i2 = q / 7, j2 = q - 7 * i2;
        a2[n] = (i2 * 13 + j2) * 3;
        qok[n] = (q < MMTOK);
    }

    for (int h = 0; h < 3; ++h) {
        // QK^T: scores strip [16 p][64 q] in registers
        bfrag qa = *(const bfrag*)&s_qk[(wv * 16 + lr) * PW_QK + h * 64 + lg * 8];
        f4 sc[4];
        #pragma unroll
        for (int n = 0; n < 4; ++n) {
            bfrag kb = *(const bfrag*)&s_qk[(n * 16 + lr) * PW_QK + h * 64 + 32 + lg * 8];
            f4 z = f4{0.f, 0.f, 0.f, 0.f};
            sc[n] = MFMA(qa, kb, z);
        }

        // scale + bias, row-max / exp / row-sum via 16-lane shuffle reduce
        float vals[4][4], mr[4], sum[4];
        #pragma unroll
        for (int r = 0; r < 4; ++r) mr[r] = -1e30f;
        #pragma unroll
        for (int n = 0; n < 4; ++n)
            #pragma unroll
            for (int r = 0; r < 4; ++r) {
                int bidx = a1[r] - a2[n] + 252 + h;
                bidx = bidx < 0 ? 0 : (bidx > 506 ? 506 : bidx);
                float s = qok[n] ? sc[n][r] * inv_scale + s_bias[bidx] : -1e30f;
                vals[n][r] = s;
                mr[r] = fmaxf(mr[r], s);
            }
        #pragma unroll
        for (int m = 1; m <= 8; m <<= 1)
            #pragma unroll
            for (int r = 0; r < 4; ++r) mr[r] = fmaxf(mr[r], __shfl_xor(mr[r], m));
        #pragma unroll
        for (int r = 0; r < 4; ++r) sum[r] = 0.f;
        #pragma unroll
        for (int n = 0; n < 4; ++n)
            #pragma unroll
            for (int r = 0; r < 4; ++r) {
                float e = qok[n] ? __expf(vals[n][r] - mr[r]) : 0.f;
                vals[n][r] = e;
                sum[r] += e;
            }
        #pragma unroll
        for (int m = 1; m <= 8; m <<= 1)
            #pragma unroll
            for (int r = 0; r < 4; ++r) sum[r] += __shfl_xor(sum[r], m);
        float inv[4];
        #pragma unroll
        for (int r = 0; r < 4; ++r) inv[r] = 1.0f / sum[r];

        // write normalized P (bf16), zeros for q>=49 keep PV K-padding clean
        #pragma unroll
        for (int n = 0; n < 4; ++n)
            #pragma unroll
            for (int r = 0; r < 4; ++r)
                s_P[(trow + r) * PW_P + n * 16 + lr] = __float2bfloat16(vals[n][r] * inv[r]);
        __syncthreads();   // safety: guarantee P visible before frag reads

        // PV: O strip [16 p][32 d] = P[16][64] x V[64][32]
        bfrag pa[2];
        #pragma unroll
        for (int kb2 = 0; kb2 < 2; ++kb2)
            pa[kb2] = *(const bfrag*)&s_P[(wv * 16 + lr) * PW_P + kb2 * 32 + lg * 8];
        #pragma unroll
        for (int n = 0; n < 2; ++n) {
            f4 oc = f4{0.f, 0.f, 0.f, 0.f};
            #pragma unroll
            for (int kb2 = 0; kb2 < 2; ++kb2) {
                bfrag vb = *(const bfrag*)&s_vT[(h * 32 + n * 16 + lr) * PW_VT + kb2 * 32 + lg * 8];
                oc = MFMA(pa[kb2], vb, oc);
            }
            #pragma unroll
            for (int r = 0; r < 4; ++r)
                s_win[(trow + r) * PW_WIN + h * 32 + n * 16 + lr] = __float2bfloat16(oc[r]);
        }
        __syncthreads();   // P reused next head
    }

    // ==== output projection ====
    for (int idx = tid; idx < 96 * 12; idx += 256) {
        int r = idx / 12, c8 = (idx - r * 12) * 8;
        *(uint4*)&s_w[r * PW_W + c8] = *(const uint4*)&OW[r * 96 + c8];
    }
    __syncthreads();

    bfrag sa[3];
    #pragma unroll
    for (int k = 0; k < 3; ++k)
        sa[k] = *(const bfrag*)&s_win[(wv * 16 + lr) * PW_WIN + k * 32 + lg * 8];
    f4 yac[6];
    #pragma unroll
    for (int n = 0; n < 6; ++n) {
        float bb = __bfloat162float(OB[n * 16 + lr]);
        yac[n] = f4{bb, bb, bb, bb};
    }
    #pragma unroll
    for (int k = 0; k < 3; ++k)
        #pragma unroll
        for (int n = 0; n < 6; ++n) {
            bfrag wb = *(const bfrag*)&s_w[(n * 16 + lr) * PW_W + k * 32 + lg * 8];
            yac[n] = MFMA(sa[k], wb, yac[n]);
        }

    // store: flat = w*49 + t ; out[b][o][flat/224][flat%224]
    #pragma unroll
    for (int n = 0; n < 6; ++n) {
        int o = n * 16 + lr;
        #pragma unroll
        for (int r = 0; r < 4; ++r) {
            int t = trow + r;
            if (t < MMTOK) {
                int flat = w * MMTOK + t;
                int ho = flat / HWD, wo = flat - ho * HWD;
                out[((b * CH + o) * HWD + ho) * HWD + wo] = yac[n][r];
            }
        }
    }
}

extern "C" void kernel_launch(void* const* d_in, const int* in_sizes, int n_in,
                              void* d_out, int out_size, void* d_ws, size_t ws_size,
                              hipStream_t stream) {
    const float* x  = (const float*)d_in[0];
    const float* qw = (const float*)d_in[1];
    const float* qb = (const float*)d_in[2];
    const float* bt = (const float*)d_in[3];
    const float* ow = (const float*)d_in[4];
    const float* ob = (const float*)d_in[5];
    float* out      = (float*)d_out;
    __hip_bfloat16* ws = (__hip_bfloat16*)d_ws;

    cvt_weights<<<(WS_TOT + 255) / 256, 256, 0, stream>>>(qw, qb, ow, ob, bt, ws);

    int B = in_sizes[0] / (CH * HWD * HWD);      // 16
    int nblocks = B * 1024;                      // one block per window (16384, %8==0)
    wmsa_mfma<<<nblocks, 256, 0, stream>>>(x, ws, out);
}